// Round 1
// 434.814 us; speedup vs baseline: 1.1133x; 1.1133x over previous
//
#include <hip/hip_runtime.h>
#include <hip/hip_bf16.h>

// PointCloudNetPersistencePrediction — round 20: pack both banks into ONE
// 16-row B (bank1 rows 0-3: x,y,z,ones-chain; bank2 rows 4-15: U-chain).
// DUAL template eliminated: all 24 applies are the single-bank kernel at
// full occupancy (4 blocks/CU vs DUAL's 2). Step-8 buildU writes U into
// rows 4-15 of its own output buffer; phase-2 lvl saves carry both banks
// (slot 3 rows 0-2 = bank1 t16 low-pass, rows 4-15 = U t8).
// Epilogue thread->element remapped (n = tid>>5, row = tid&31) so all
// global out/lvl/cur/ihd accesses are fully coalesced (was 8-16x write
// amplification); LDS partial reads become 8-way conflicted, negligible.

#define NN 2048
#define NPAIR 16

typedef _Float16 half8 __attribute__((ext_vector_type(8)));
typedef _Float16 f16x2 __attribute__((ext_vector_type(2)));
typedef float f32x4 __attribute__((ext_vector_type(4)));

extern "C" __device__ f16x2 __ocml_exp2_2f16(f16x2);   // packed v_exp_f16

#define C2F 0.28853900817779268f   //  0.2 * log2(e)
#define CWF -0.14426950408889634f  // -0.1 * log2(e)
#define NL2T 3.3219280948873623f   // -log2(0.1); qi' = qi + NL2T

// ---- init+pack fused: Xs fp32 [p][i][{x,y,z,q}]; XT fp16 [p][16][2048]
//      (row3 = ones -> deg via MFMA); Xp packed fp16 j-pair entries ----
__global__ __launch_bounds__(256) void initpack_k(const float* __restrict__ pc,
                                                  const float* __restrict__ alphas,
                                                  float* __restrict__ Xs,
                                                  _Float16* __restrict__ XT,
                                                  _Float16* __restrict__ Xp) {
    int gid = blockIdx.x * 256 + threadIdx.x;
    if (gid >= NPAIR * NN) return;
    int p = gid >> 11, i = gid & (NN - 1);
    int b = p >> 2, k = p & 3;
    const float* pcr = pc + ((size_t)b * NN + i) * 3;
    const float* al  = alphas + k * 3;
    float x = pcr[0] * al[0], y = pcr[1] * al[1], z = pcr[2] * al[2];
    float q = CWF * (x * x + y * y + z * z);
    float4 o; o.x = x; o.y = y; o.z = z; o.w = q;
    ((float4*)Xs)[gid] = o;
    _Float16* xt = XT + (size_t)p * 16 * NN + i;
    xt[0 * NN] = (_Float16)x;
    xt[1 * NN] = (_Float16)y;
    xt[2 * NN] = (_Float16)z;
    xt[3 * NN] = (_Float16)1.0f;
#pragma unroll
    for (int n = 4; n < 16; ++n) xt[n * NN] = (_Float16)0.f;
    _Float16* xp = Xp + ((size_t)p * 1024 + (i >> 1)) * 8 + (i & 1);
    xp[0] = (_Float16)x; xp[2] = (_Float16)y;
    xp[4] = (_Float16)z; xp[6] = (_Float16)q;
}

// ---- fused apply: out = f16(0.5*cur + ihd (x) (W@cur^T)^T).
// 512 thr = 8 K-waves (chunk 256); lane: s=2 m-subtiles; M=32; grid (64,16).
// BUILDU: step-8 epilogue emits U into rows 4-15 of out (combined bank);
// t=8 cols 0-2 stashed via 96-float LDS for the jw=3 wavelet.
template<bool FIRST, bool BUILDU>
__global__ __launch_bounds__(512, 8)
void apply_k(const float* __restrict__ Xs, const _Float16* __restrict__ Xp,
             float* __restrict__ ihd,
             const _Float16* __restrict__ cur, _Float16* __restrict__ out,
             float* __restrict__ lvl, int t,
             const float* __restrict__ LT1u) {
    __shared__ __align__(16) float smem[4352];
    const int tid  = threadIdx.x;
    const int lane = tid & 63;
    const int wv   = tid >> 6;                     // K-group 0..7
    const int p    = blockIdx.y;
    const int m0   = blockIdx.x * 32;
    const int idx16 = lane & 15, quad = lane >> 4;

    {
        const float4* src = (const float4*)(Xp + (size_t)p * 8192);
        float4* dst = (float4*)smem;
        dst[tid]       = src[tid];
        dst[tid + 512] = src[tid + 512];
    }
    __syncthreads();

    f16x2 qi2[2], xx2[2], xy2[2], xz2[2];
#pragma unroll
    for (int s = 0; s < 2; ++s) {
        float4 v = *(const float4*)(Xs + ((size_t)p * NN + m0 + s * 16 + idx16) * 4);
        _Float16 q = (_Float16)(v.w + NL2T);
        _Float16 x = (_Float16)(C2F * v.x);
        _Float16 y = (_Float16)(C2F * v.y);
        _Float16 z = (_Float16)(C2F * v.z);
        qi2[s] = (f16x2){q, q}; xx2[s] = (f16x2){x, x};
        xy2[s] = (f16x2){y, y}; xz2[s] = (f16x2){z, z};
    }
    const f16x2 SC2 = (f16x2){(_Float16)32768.f, (_Float16)32768.f};

    const _Float16* bp = cur + ((size_t)p * 16 + idx16) * NN + wv * 256 + quad * 8;
    f32x4 acc[2] = {{0.f,0.f,0.f,0.f},{0.f,0.f,0.f,0.f}};

    for (int kc = 0; kc < 8; ++kc) {
        const int pb = wv * 128 + kc * 16 + quad * 4;  // j-pair entry base
        half8 bf = *(const half8*)(bp + kc * 32);
        union { f16x2 h2[4]; half8 h8; } af[2];
#pragma unroll
        for (int jp = 0; jp < 4; ++jp) {
            union { float4 f; f16x2 h[4]; } e;
            e.f = ((const float4*)smem)[pb + jp];      // {x2,y2,z2,q2} for 2 j
#pragma unroll
            for (int s = 0; s < 2; ++s) {
                f16x2 tv = qi2[s] + e.h[3];
                tv = __builtin_elementwise_fma(xx2[s], e.h[0], tv);
                tv = __builtin_elementwise_fma(xy2[s], e.h[1], tv);
                tv = __builtin_elementwise_fma(xz2[s], e.h[2], tv);
                // threshold folded into exp arg: t'<0 -> arg<=-24 -> exp2 = 0
                f16x2 u = __builtin_elementwise_min(tv, tv * SC2);
                af[s].h2[jp] = __ocml_exp2_2f16(u);    // = 10*w (2^3.32 fold)
            }
        }
#pragma unroll
        for (int s = 0; s < 2; ++s)
            acc[s] = __builtin_amdgcn_mfma_f32_16x16x32_f16(af[s].h8, bf, acc[s], 0, 0, 0);
    }

    // ---- epilogue (coalesced mapping: n = tid>>5, row = m0 + (tid&31)) ----
    const int n  = tid >> 5;                        // output row of [16][NN]
    const int rr = tid & 31;                        // row within m-block
    const int s2 = rr >> 4, mloc = rr & 15;
    const int base = s2 * 256 + (mloc >> 2) * 64 + (mloc & 3);
    const int row = m0 + rr;
    float ihEff;
    if (!FIRST) ihEff = 0.1f * ihd[p * NN + row];

    __syncthreads();
#pragma unroll
    for (int s = 0; s < 2; ++s)
        *(f32x4*)&smem[wv * 512 + s * 256 + lane * 4] = acc[s];
    __syncthreads();

    float sum = 0.f;                               // = 10*(W@B)
#pragma unroll
    for (int g = 0; g < 8; ++g) sum += smem[g * 512 + base + n * 4];
    if (FIRST) {
        float deg10 = 0.f;                         // = 10*deg (col 3 = ones)
#pragma unroll
        for (int g = 0; g < 8; ++g) deg10 += smem[g * 512 + base + 12];
        float ih = 5.0f / deg10;                   // = 0.5/deg
        if (n == 3) ihd[p * NN + row] = ih;
        ihEff = 0.1f * ih;
    }
    float cv = (float)cur[((size_t)p * 16 + n) * NN + row];
    float o1v = 0.5f * cv + ihEff * sum;
    if (lvl) lvl[(((size_t)p * 5 + t) * 16 + n) * NN + row] = o1v;

    if (!BUILDU) {
        out[((size_t)p * 16 + n) * NN + row] = (_Float16)o1v;
    } else {
        // stash fresh t=8 (rows 0-2), then overwrite rows 4-15 with U
        if (n < 3) smem[4096 + n * 32 + rr] = o1v;
        __syncthreads();
        float oval = o1v;                          // rows 0-3: t=8 state
        if (n >= 4) {                              // rows 4-15: U = |psi_jw|_c
            const int u = n - 4, jw = u / 3, c = u - 3 * jw;
            float a = (jw == 0) ? Xs[((size_t)p * NN + row) * 4 + c]
                                : LT1u[(((size_t)p * 5 + (jw - 1)) * 16 + c) * NN + row];
            float bb = (jw == 3) ? smem[4096 + c * 32 + rr]
                                 : LT1u[(((size_t)p * 5 + jw) * 16 + c) * NN + row];
            oval = fabsf(a - bb);
        }
        out[((size_t)p * 16 + n) * NN + row] = (_Float16)oval;
    }
}

// ---- final mean over N of 48 features ----
// LT1 slots 0-3: bank1 t=1,2,4,8 (rows 0-2 live).
// LT2 slots 0-4: combined t=1,2,4,8,16 of the U-chain (rows 4-15), with
// slot 3 rows 0-2 additionally = bank1 t=16 (low-pass).
__global__ __launch_bounds__(64) void reduce_k(const float* __restrict__ Xs,
                                               const float* __restrict__ LT1,
                                               const float* __restrict__ LT2,
                                               float* __restrict__ out) {
    int f = blockIdx.x, p = blockIdx.y, lane = threadIdx.x;
    const float* l1 = LT1 + (size_t)p * 5 * 16 * NN;
    const float* l2 = LT2 + (size_t)p * 5 * 16 * NN;
    float s = 0.f;
    for (int m = lane; m < NN; m += 64) {
        float v;
        if (f < 3) {
            v = l2[((size_t)3 * 16 + f) * NN + m];            // P^16 F
        } else if (f < 18) {
            int j = (f - 3) / 3, c = (f - 3) % 3;
            float a = (j == 0) ? Xs[((size_t)p * NN + m) * 4 + c]
                               : l1[((size_t)(j - 1) * 16 + c) * NN + m];
            float b = (j < 4) ? l1[((size_t)j * 16 + c) * NN + m]
                              : l2[((size_t)3 * 16 + c) * NN + m];  // t16
            v = fabsf(a - b);
        } else {
            int gg = f - 18, j2, uc;
            if (gg < 3)       { j2 = 1; uc = gg; }
            else if (gg < 9)  { j2 = 2; uc = gg - 3; }
            else if (gg < 18) { j2 = 3; uc = gg - 9; }
            else              { j2 = 4; uc = gg - 18; }
            v = fabsf(l2[((size_t)(j2 - 1) * 16 + uc + 4) * NN + m]
                    - l2[((size_t)j2 * 16 + uc + 4) * NN + m]);
        }
        s += v;
    }
#pragma unroll
    for (int off = 32; off > 0; off >>= 1) s += __shfl_down(s, off, 64);
    if (lane == 0) out[p * 48 + f] = s * (1.0f / NN);
}

extern "C" void kernel_launch(void* const* d_in, const int* in_sizes, int n_in,
                              void* d_out, int out_size, void* d_ws, size_t ws_size,
                              hipStream_t stream) {
    const float* pc     = (const float*)d_in[0];
    const float* alphas = (const float*)d_in[1];
    float* outp = (float*)d_out;

    char* base = (char*)d_ws;
    size_t off = 0;
    auto carve = [&](size_t bytes) -> void* {
        void* r = base + off;
        off = (off + bytes + 255) & ~(size_t)255;
        return r;
    };
    float*     Xs  = (float*)carve((size_t)NPAIR * NN * 4 * sizeof(float));
    _Float16*  Xp  = (_Float16*)carve((size_t)NPAIR * 1024 * 8 * 2);
    float*     ihd = (float*)carve((size_t)NPAIR * NN * sizeof(float));
    _Float16*  XT  = (_Float16*)carve((size_t)NPAIR * 16 * NN * 2);
    _Float16*  pA  = (_Float16*)carve((size_t)NPAIR * 16 * NN * 2);
    _Float16*  pB  = (_Float16*)carve((size_t)NPAIR * 16 * NN * 2);
    float*     LT1 = (float*)carve((size_t)NPAIR * 5 * 16 * NN * sizeof(float));
    float*     LT2 = (float*)carve((size_t)NPAIR * 5 * 16 * NN * sizeof(float));

    dim3 gridA(NN / 32, NPAIR);   // 64 x 16 = 1024 blocks

    initpack_k<<<dim3((NPAIR * NN) / 256), 256, 0, stream>>>(pc, alphas, Xs, XT, Xp);

    // phase 1: bank1 steps 1..8 (t=1,2,4,8 -> LT1 slots 0..3); step 8 also
    // packs U into rows 4-15 of its output (combined bank).
    const _Float16* c1 = XT;
    int slot = 0;
    for (int step = 1; step <= 8; ++step) {
        _Float16* o1 = (c1 == pA) ? pB : pA;
        bool sv = (step & (step - 1)) == 0;
        float* lv = sv ? LT1 : nullptr;
        if (step == 1)
            apply_k<true, false><<<gridA, 512, 0, stream>>>(Xs, Xp, ihd,
                c1, o1, lv, slot, nullptr);
        else if (step == 8)
            apply_k<false, true><<<gridA, 512, 0, stream>>>(Xs, Xp, ihd,
                c1, o1, lv, slot, LT1);
        else
            apply_k<false, false><<<gridA, 512, 0, stream>>>(Xs, Xp, ihd,
                c1, o1, lv, slot, nullptr);
        if (sv) ++slot;
        c1 = o1;
    }

    // phase 2: combined bank, 16 uniform single steps.
    // saves at i = 1,2,4,8,16 -> LT2 slots 0..4 (slot 3 rows 0-2 double as
    // bank1 t=16 low-pass; rows 4-15 are the diffused-U chain).
    int slot2 = 0;
    for (int i = 1; i <= 16; ++i) {
        _Float16* o1 = (c1 == pA) ? pB : pA;
        bool sv = (i & (i - 1)) == 0;
        float* lv = sv ? LT2 : nullptr;
        apply_k<false, false><<<gridA, 512, 0, stream>>>(Xs, Xp, ihd,
            c1, o1, lv, slot2, nullptr);
        if (sv) ++slot2;
        c1 = o1;
    }

    reduce_k<<<dim3(48, NPAIR), 64, 0, stream>>>(Xs, LT1, LT2, outp);
}